// Round 4
// baseline (646.818 us; speedup 1.0000x reference)
//
#include <hip/hip_runtime.h>
#include <math.h>

__device__ __forceinline__ float f4c(const float4& v, int t) {
  return t == 0 ? v.x : t == 1 ? v.y : t == 2 ? v.z : v.w;
}

// ---------------- CSR build ----------------
__global__ void histo_kernel(const int* __restrict__ ei, int E, int N,
                             int* __restrict__ counts) {
  int e = blockIdx.x * blockDim.x + threadIdx.x;
  int etot = E + N;
  if (e >= etot) return;
  int d = (e < E) ? ei[E + e] : (e - E);
  atomicAdd(&counts[d], 1);
}

__global__ void scan1_kernel(const int* __restrict__ counts, int* __restrict__ excl,
                             int* __restrict__ bsums, int N) {
  __shared__ int sm[256];
  int t = threadIdx.x;
  int i = blockIdx.x * 256 + t;
  int v = (i < N) ? counts[i] : 0;
  sm[t] = v;
  __syncthreads();
#pragma unroll
  for (int off = 1; off < 256; off <<= 1) {
    int add = (t >= off) ? sm[t - off] : 0;
    __syncthreads();
    sm[t] += add;
    __syncthreads();
  }
  if (i < N) excl[i] = sm[t] - v;
  if (t == 255) bsums[blockIdx.x] = sm[255];
}

__global__ void scan2_kernel(int* __restrict__ bsums, int nb) {
  __shared__ int sm[256];
  int t = threadIdx.x;
  int v = (t < nb) ? bsums[t] : 0;
  sm[t] = v;
  __syncthreads();
#pragma unroll
  for (int off = 1; off < 256; off <<= 1) {
    int add = (t >= off) ? sm[t - off] : 0;
    __syncthreads();
    sm[t] += add;
    __syncthreads();
  }
  if (t < nb) bsums[t] = sm[t] - v;  // exclusive
}

__global__ void scan3_kernel(const int* __restrict__ excl, const int* __restrict__ bsums,
                             int* __restrict__ rowptr, int* __restrict__ cursor,
                             int N, int etot) {
  int i = blockIdx.x * 256 + threadIdx.x;
  if (i < N) {
    int v = excl[i] + bsums[i >> 8];
    rowptr[i] = v;
    cursor[i] = v;
  }
  if (i == N) rowptr[N] = etot;
}

__global__ void scatter_kernel(const int* __restrict__ ei, int E, int N,
                               int* __restrict__ cursor, int* __restrict__ csr_src) {
  int e = blockIdx.x * blockDim.x + threadIdx.x;
  int etot = E + N;
  if (e >= etot) return;
  int s, d;
  if (e < E) { s = ei[e]; d = ei[E + e]; } else { s = e - E; d = e - E; }
  int pos = atomicAdd(&cursor[d], 1);
  csr_src[pos] = s;
}

// ---------------- degree counting-sort (load balance for groups-as-nodes) ----
__global__ void deghist_kernel(const int* __restrict__ rowptr, int N,
                               int* __restrict__ dhist) {
  int i = blockIdx.x * 256 + threadIdx.x;
  if (i >= N) return;
  int d = rowptr[i + 1] - rowptr[i];
  int key = d < 1023 ? d : 1023;
  atomicAdd(&dhist[key], 1);
}

__global__ void degscan_kernel(int* __restrict__ dhist) {  // 1 block x 1024
  __shared__ int sm[1024];
  int t = threadIdx.x;
  int v = dhist[t];
  sm[t] = v;
  __syncthreads();
#pragma unroll
  for (int off = 1; off < 1024; off <<= 1) {
    int add = (t >= off) ? sm[t - off] : 0;
    __syncthreads();
    sm[t] += add;
    __syncthreads();
  }
  dhist[t] = sm[t] - v;  // exclusive
}

__global__ void degscatter_kernel(const int* __restrict__ rowptr, int N,
                                  int* __restrict__ dhist, int* __restrict__ perm) {
  int i = blockIdx.x * 256 + threadIdx.x;
  if (i >= N) return;
  int d = rowptr[i + 1] - rowptr[i];
  int key = d < 1023 ? d : 1023;
  int pos = atomicAdd(&dhist[key], 1);
  perm[pos] = i;
}

// ---------------- GEMM: H = X(N x 128) @ W(128 x COLS) + hl/hr epilogue -------
template <int COLS>
__global__ __launch_bounds__(256) void gemm_kernel(
    const float* __restrict__ X, const float* __restrict__ W,
    const float* __restrict__ al, const float* __restrict__ ar,
    float* __restrict__ H, float* __restrict__ hl, float* __restrict__ hr, int N) {
  constexpr int KC = 64;
  constexpr int XS = KC + 4;  // 2-way bank alias (free)
  __shared__ float Ws[KC * COLS];
  __shared__ float Xs[64 * XS];
  const int tid = threadIdx.x;
  const int tx = tid & 15, ty = tid >> 4;
  const int r0 = blockIdx.x * 64;

  float acc[4][2][4];
#pragma unroll
  for (int i = 0; i < 4; ++i)
#pragma unroll
    for (int h = 0; h < 2; ++h)
#pragma unroll
      for (int j = 0; j < 4; ++j) acc[i][h][j] = 0.f;

  for (int k0 = 0; k0 < 128; k0 += KC) {
    __syncthreads();
    constexpr int WQ = KC * COLS / 4;
    const float4* wg = (const float4*)(W + k0 * COLS);
#pragma unroll
    for (int i = tid; i < WQ; i += 256) ((float4*)Ws)[i] = wg[i];
#pragma unroll
    for (int i = tid; i < 64 * KC / 4; i += 256) {
      int row = i >> 4;
      int kq = i & 15;
      int gr = r0 + row;
      if (gr > N - 1) gr = N - 1;
      float4 v = *(const float4*)(X + (size_t)gr * 128 + k0 + kq * 4);
      *(float4*)(&Xs[row * XS + kq * 4]) = v;
    }
    __syncthreads();
#pragma unroll
    for (int kk0 = 0; kk0 < KC; kk0 += 4) {
      float4 xv[4];
#pragma unroll
      for (int i = 0; i < 4; ++i)
        xv[i] = *(const float4*)(&Xs[(ty * 4 + i) * XS + kk0]);
#pragma unroll
      for (int t = 0; t < 4; ++t) {
        float4 w0 = *(const float4*)(&Ws[(kk0 + t) * COLS + tx * 4]);
        float4 w1;
        if constexpr (COLS == 128) w1 = *(const float4*)(&Ws[(kk0 + t) * COLS + 64 + tx * 4]);
#pragma unroll
        for (int i = 0; i < 4; ++i) {
          float xk = f4c(xv[i], t);
          acc[i][0][0] = fmaf(xk, w0.x, acc[i][0][0]);
          acc[i][0][1] = fmaf(xk, w0.y, acc[i][0][1]);
          acc[i][0][2] = fmaf(xk, w0.z, acc[i][0][2]);
          acc[i][0][3] = fmaf(xk, w0.w, acc[i][0][3]);
          if constexpr (COLS == 128) {
            acc[i][1][0] = fmaf(xk, w1.x, acc[i][1][0]);
            acc[i][1][1] = fmaf(xk, w1.y, acc[i][1][1]);
            acc[i][1][2] = fmaf(xk, w1.z, acc[i][1][2]);
            acc[i][1][3] = fmaf(xk, w1.w, acc[i][1][3]);
          }
        }
      }
    }
  }

  float4 alv0 = *(const float4*)(al + tx * 4);
  float4 arv0 = *(const float4*)(ar + tx * 4);
  float4 alv1, arv1;
  if constexpr (COLS == 128) {
    alv1 = *(const float4*)(al + 64 + tx * 4);
    arv1 = *(const float4*)(ar + 64 + tx * 4);
  }
#pragma unroll
  for (int i = 0; i < 4; ++i) {
    int r = r0 + ty * 4 + i;
    bool ok = r < N;
    float4 o0 = make_float4(acc[i][0][0], acc[i][0][1], acc[i][0][2], acc[i][0][3]);
    float pl = o0.x * alv0.x + o0.y * alv0.y + o0.z * alv0.z + o0.w * alv0.w;
    float pr = o0.x * arv0.x + o0.y * arv0.y + o0.z * arv0.z + o0.w * arv0.w;
    if (ok) *(float4*)(&H[(size_t)r * COLS + tx * 4]) = o0;
    if constexpr (COLS == 128) {
      float4 o1 = make_float4(acc[i][1][0], acc[i][1][1], acc[i][1][2], acc[i][1][3]);
      pl += o1.x * alv1.x + o1.y * alv1.y + o1.z * alv1.z + o1.w * alv1.w;
      pr += o1.x * arv1.x + o1.y * arv1.y + o1.z * arv1.z + o1.w * arv1.w;
      if (ok) *(float4*)(&H[(size_t)r * COLS + 64 + tx * 4]) = o1;
    }
#pragma unroll
    for (int off = 1; off < 16; off <<= 1) {
      pl += __shfl_xor(pl, off);
      pr += __shfl_xor(pr, off);
    }
    if (ok && tx == 0) {
      hl[r] = pl;
      hr[r] = pr;
    }
  }
}

// ---------------- per-node attention + aggregation ----------------
// Wave = 8 groups x 8 lanes. Each GROUP owns one node (degree-sorted via perm,
// so the 8 nodes in a wave have near-equal degree -> minimal divergence).
// Lane l owns feature elements [l*EPL, (l+1)*EPL). Defer-max online softmax:
// keep m from first edge, only rescale if alpha jumps by >30 (exp headroom).
template <int COLS, bool LAST>
__global__ __launch_bounds__(256) void node_kernel(
    const float* __restrict__ H, const float* __restrict__ hl,
    const float* __restrict__ hr, const int* __restrict__ rowptr,
    const int* __restrict__ csr_src, const int* __restrict__ perm,
    const float* __restrict__ b, float* __restrict__ OUT, int N) {
  constexpr int GS = 8;
  constexpr int EPL = COLS / GS;  // 16 (COLS=128) or 8 (COLS=64)
  constexpr int NF4 = EPL / 4;
  const int lane = threadIdx.x & 63;
  const int g = lane >> 3, l = lane & 7;
  const int wv = blockIdx.x * 4 + (threadIdx.x >> 6);
  const int idx = wv * GS + g;
  const bool active = idx < N;
  const int node = active ? perm[idx] : 0;

  float hi[EPL];
  {
    const float* hp = H + (size_t)node * COLS + l * EPL;
#pragma unroll
    for (int q = 0; q < NF4; ++q) *(float4*)&hi[q * 4] = *(const float4*)(hp + q * 4);
  }
  const float hri = hr[node];
  int e = active ? rowptr[node] : 0;
  const int end = active ? rowptr[node + 1] : 0;

  float m = -INFINITY, sumw = 0.f;
  float acc[EPL];
#pragma unroll
  for (int j = 0; j < EPL; ++j) acc[j] = 0.f;

  int s;
  float hls;
  float hv[EPL];
  if (e < end) {
    s = csr_src[e];
    hls = hl[s];
    const float* hp = H + (size_t)s * COLS + l * EPL;
#pragma unroll
    for (int q = 0; q < NF4; ++q) *(float4*)&hv[q * 4] = *(const float4*)(hp + q * 4);
  }

  for (; e < end; ++e) {
    float ch[EPL];
#pragma unroll
    for (int j = 0; j < EPL; ++j) ch[j] = hv[j];
    const float chl = hls;
    if (e + 1 < end) {  // group-uniform prefetch
      s = csr_src[e + 1];
      hls = hl[s];
      const float* hp = H + (size_t)s * COLS + l * EPL;
#pragma unroll
      for (int q = 0; q < NF4; ++q) *(float4*)&hv[q * 4] = *(const float4*)(hp + q * 4);
    }
    float d = 0.f;
#pragma unroll
    for (int j = 0; j < EPL; ++j) d = fmaf(hi[j], ch[j], d);
    d += __shfl_xor(d, 1);
    d += __shfl_xor(d, 2);
    d += __shfl_xor(d, 4);
    float gate = 1.f / (1.f + __expf(-d));
    float a = (chl + hri) * gate;
    a = (a >= 0.f) ? a : 0.2f * a;
    float dm = a - m;
    if (dm > 30.f) {             // first edge (m=-inf) or rare big jump
      float sc = __expf(-dm);    // exp(m - a); first edge: exp(-inf) = 0
      sumw *= sc;
#pragma unroll
      for (int j = 0; j < EPL; ++j) acc[j] *= sc;
      m = a;
      dm = 0.f;
    }
    float w = __expf(dm);        // may exceed 1 (bounded by e^30) - f32 safe
    sumw += w;
#pragma unroll
    for (int j = 0; j < EPL; ++j) acc[j] = fmaf(w, ch[j], acc[j]);
  }

  if (!active) return;
  const float inv = 1.f / (sumw + 1e-16f);
  float o[EPL];
  const float* bp = b + l * EPL;
#pragma unroll
  for (int j = 0; j < EPL; ++j) o[j] = fmaxf(acc[j] * inv + bp[j], 0.f);

  if constexpr (LAST) {
    // COLS == 64, EPL == 8: log_softmax over the group's 64 values
    float mx = o[0];
#pragma unroll
    for (int j = 1; j < EPL; ++j) mx = fmaxf(mx, o[j]);
    mx = fmaxf(mx, __shfl_xor(mx, 1));
    mx = fmaxf(mx, __shfl_xor(mx, 2));
    mx = fmaxf(mx, __shfl_xor(mx, 4));
    float es = 0.f;
#pragma unroll
    for (int j = 0; j < EPL; ++j) es += __expf(o[j] - mx);
    es += __shfl_xor(es, 1);
    es += __shfl_xor(es, 2);
    es += __shfl_xor(es, 4);
    float ls = logf(es);
#pragma unroll
    for (int q = 0; q < NF4; ++q) {
      float4 ov = make_float4(o[q * 4 + 0] - mx - ls, o[q * 4 + 1] - mx - ls,
                              o[q * 4 + 2] - mx - ls, o[q * 4 + 3] - mx - ls);
      *(float4*)(&OUT[(size_t)node * COLS + l * EPL + q * 4]) = ov;
    }
  } else {
#pragma unroll
    for (int q = 0; q < NF4; ++q) {
      float4 ov = make_float4(o[q * 4 + 0], o[q * 4 + 1], o[q * 4 + 2], o[q * 4 + 3]);
      *(float4*)(&OUT[(size_t)node * COLS + l * EPL + q * 4]) = ov;
    }
  }
}

// ---------------- launch ----------------
extern "C" void kernel_launch(void* const* d_in, const int* in_sizes, int n_in,
                              void* d_out, int out_size, void* d_ws, size_t ws_size,
                              hipStream_t stream) {
  const float* x = (const float*)d_in[0];
  const int* ei = (const int*)d_in[1];
  const float* W0 = (const float*)d_in[2];
  const float* al0 = (const float*)d_in[3];
  const float* ar0 = (const float*)d_in[4];
  const float* b0 = (const float*)d_in[5];
  const float* W1 = (const float*)d_in[6];
  const float* al1 = (const float*)d_in[7];
  const float* ar1 = (const float*)d_in[8];
  const float* b1 = (const float*)d_in[9];
  const float* W2 = (const float*)d_in[10];
  const float* al2 = (const float*)d_in[11];
  const float* ar2 = (const float*)d_in[12];
  const float* b2 = (const float*)d_in[13];

  const int N = in_sizes[0] / 128;  // 50000
  const int E = in_sizes[1] / 2;    // 640000
  const int ETOT = E + N;

  char* p = (char*)d_ws;
  auto carve = [&](size_t bytes) {
    void* r = (void*)p;
    p += (bytes + 255) & ~(size_t)255;
    return r;
  };
  float* hA = (float*)carve((size_t)N * 128 * sizeof(float));
  float* hB = (float*)carve((size_t)N * 128 * sizeof(float));
  float* hl = (float*)carve((size_t)N * sizeof(float));
  float* hr = (float*)carve((size_t)N * sizeof(float));
  int* counts = (int*)carve((size_t)N * sizeof(int));
  int* excl = (int*)carve((size_t)N * sizeof(int));
  int* bsums = (int*)carve(1024 * sizeof(int));
  int* rowptr = (int*)carve((size_t)(N + 1) * sizeof(int));
  int* cursor = (int*)carve((size_t)(N + 1) * sizeof(int));
  int* csr_src = (int*)carve((size_t)ETOT * sizeof(int));
  int* dhist = (int*)carve(1024 * sizeof(int));
  int* perm = (int*)carve((size_t)N * sizeof(int));

  // ---- CSR build ----
  hipMemsetAsync(counts, 0, (size_t)N * sizeof(int), stream);
  hipMemsetAsync(dhist, 0, 1024 * sizeof(int), stream);
  {
    int nb = (ETOT + 255) / 256;
    histo_kernel<<<nb, 256, 0, stream>>>(ei, E, N, counts);
  }
  int nbs = (N + 255) / 256;
  scan1_kernel<<<nbs, 256, 0, stream>>>(counts, excl, bsums, N);
  scan2_kernel<<<1, 256, 0, stream>>>(bsums, nbs);
  scan3_kernel<<<(N + 256) / 256 + 1, 256, 0, stream>>>(excl, bsums, rowptr, cursor, N, ETOT);
  {
    int nb = (ETOT + 255) / 256;
    scatter_kernel<<<nb, 256, 0, stream>>>(ei, E, N, cursor, csr_src);
  }
  // ---- degree sort ----
  deghist_kernel<<<nbs, 256, 0, stream>>>(rowptr, N, dhist);
  degscan_kernel<<<1, 1024, 0, stream>>>(dhist);
  degscatter_kernel<<<nbs, 256, 0, stream>>>(rowptr, N, dhist, perm);

  const int gemm_grid = (N + 63) / 64;
  const int node_grid = (N + 31) / 32;  // 32 nodes per block (4 waves x 8 groups)

  gemm_kernel<128><<<gemm_grid, 256, 0, stream>>>(x, W0, al0, ar0, hA, hl, hr, N);
  node_kernel<128, false><<<node_grid, 256, 0, stream>>>(hA, hl, hr, rowptr, csr_src, perm, b0, hB, N);

  gemm_kernel<128><<<gemm_grid, 256, 0, stream>>>(hB, W1, al1, ar1, hA, hl, hr, N);
  node_kernel<128, false><<<node_grid, 256, 0, stream>>>(hA, hl, hr, rowptr, csr_src, perm, b1, hB, N);

  gemm_kernel<64><<<gemm_grid, 256, 0, stream>>>(hB, W2, al2, ar2, hA, hl, hr, N);
  node_kernel<64, true><<<node_grid, 256, 0, stream>>>(hA, hl, hr, rowptr, csr_src, perm, b2,
                                                       (float*)d_out, N);
}

// Round 5
// 350.005 us; speedup vs baseline: 1.8480x; 1.8480x over previous
//
#include <hip/hip_runtime.h>
#include <math.h>

__device__ __forceinline__ float f4c(const float4& v, int t) {
  return t == 0 ? v.x : t == 1 ? v.y : t == 2 ? v.z : v.w;
}

// ---------------- CSR build ----------------
__global__ void histo_kernel(const int* __restrict__ ei, int E, int N,
                             int* __restrict__ counts) {
  int e = blockIdx.x * blockDim.x + threadIdx.x;
  int etot = E + N;
  if (e >= etot) return;
  int d = (e < E) ? ei[E + e] : (e - E);
  atomicAdd(&counts[d], 1);
}

__global__ void scan1_kernel(const int* __restrict__ counts, int* __restrict__ excl,
                             int* __restrict__ bsums, int N) {
  __shared__ int sm[256];
  int t = threadIdx.x;
  int i = blockIdx.x * 256 + t;
  int v = (i < N) ? counts[i] : 0;
  sm[t] = v;
  __syncthreads();
#pragma unroll
  for (int off = 1; off < 256; off <<= 1) {
    int add = (t >= off) ? sm[t - off] : 0;
    __syncthreads();
    sm[t] += add;
    __syncthreads();
  }
  if (i < N) excl[i] = sm[t] - v;
  if (t == 255) bsums[blockIdx.x] = sm[255];
}

__global__ void scan2_kernel(int* __restrict__ bsums, int nb) {
  __shared__ int sm[256];
  int t = threadIdx.x;
  int v = (t < nb) ? bsums[t] : 0;
  sm[t] = v;
  __syncthreads();
#pragma unroll
  for (int off = 1; off < 256; off <<= 1) {
    int add = (t >= off) ? sm[t - off] : 0;
    __syncthreads();
    sm[t] += add;
    __syncthreads();
  }
  if (t < nb) bsums[t] = sm[t] - v;  // exclusive
}

__global__ void scan3_kernel(const int* __restrict__ excl, const int* __restrict__ bsums,
                             int* __restrict__ rowptr, int* __restrict__ cursor,
                             int N, int etot) {
  int i = blockIdx.x * 256 + threadIdx.x;
  if (i < N) {
    int v = excl[i] + bsums[i >> 8];
    rowptr[i] = v;
    cursor[i] = v;
  }
  if (i == N) rowptr[N] = etot;
}

__global__ void scatter_kernel(const int* __restrict__ ei, int E, int N,
                               int* __restrict__ cursor, int* __restrict__ csr_src) {
  int e = blockIdx.x * blockDim.x + threadIdx.x;
  int etot = E + N;
  if (e >= etot) return;
  int s, d;
  if (e < E) { s = ei[e]; d = ei[E + e]; } else { s = e - E; d = e - E; }
  int pos = atomicAdd(&cursor[d], 1);
  csr_src[pos] = s;
}

// ---------------- degree counting-sort, LDS-aggregated (no hot global atomics)
__global__ void deghist_kernel(const int* __restrict__ rowptr, int N,
                               int* __restrict__ dhist) {
  __shared__ int lh[1024];
  int t = threadIdx.x;
  for (int i = t; i < 1024; i += 256) lh[i] = 0;
  __syncthreads();
  int i = blockIdx.x * 256 + t;
  if (i < N) {
    int d = rowptr[i + 1] - rowptr[i];
    int key = d < 1023 ? d : 1023;
    atomicAdd(&lh[key], 1);
  }
  __syncthreads();
  for (int bin = t; bin < 1024; bin += 256) {
    int c = lh[bin];
    if (c) atomicAdd(&dhist[bin], c);
  }
}

__global__ void degscan_kernel(int* __restrict__ dhist) {  // 1 block x 1024
  __shared__ int sm[1024];
  int t = threadIdx.x;
  int v = dhist[t];
  sm[t] = v;
  __syncthreads();
#pragma unroll
  for (int off = 1; off < 1024; off <<= 1) {
    int add = (t >= off) ? sm[t - off] : 0;
    __syncthreads();
    sm[t] += add;
    __syncthreads();
  }
  dhist[t] = sm[t] - v;  // exclusive
}

__global__ void degscatter_kernel(const int* __restrict__ rowptr, int N,
                                  int* __restrict__ dhist, int* __restrict__ perm) {
  __shared__ int lc[1024];   // block-local bin counts / ranks
  __shared__ int lb[1024];   // block's reserved base per bin
  int t = threadIdx.x;
  for (int i = t; i < 1024; i += 256) lc[i] = 0;
  __syncthreads();
  int i = blockIdx.x * 256 + t;
  int key = 0, lr = 0;
  if (i < N) {
    int d = rowptr[i + 1] - rowptr[i];
    key = d < 1023 ? d : 1023;
    lr = atomicAdd(&lc[key], 1);  // LDS atomic: block-local rank
  }
  __syncthreads();
  for (int bin = t; bin < 1024; bin += 256) {
    int c = lc[bin];
    if (c) lb[bin] = atomicAdd(&dhist[bin], c);  // one returning atomic per (block,bin)
  }
  __syncthreads();
  if (i < N) perm[lb[key] + lr] = i;
}

// ---------------- GEMM: H = X(N x 128) @ W(128 x COLS) + hl/hr epilogue -------
template <int COLS>
__global__ __launch_bounds__(256) void gemm_kernel(
    const float* __restrict__ X, const float* __restrict__ W,
    const float* __restrict__ al, const float* __restrict__ ar,
    float* __restrict__ H, float* __restrict__ hl, float* __restrict__ hr, int N) {
  constexpr int KC = 64;
  constexpr int XS = KC + 4;  // 2-way bank alias (free)
  __shared__ float Ws[KC * COLS];
  __shared__ float Xs[64 * XS];
  const int tid = threadIdx.x;
  const int tx = tid & 15, ty = tid >> 4;
  const int r0 = blockIdx.x * 64;

  float acc[4][2][4];
#pragma unroll
  for (int i = 0; i < 4; ++i)
#pragma unroll
    for (int h = 0; h < 2; ++h)
#pragma unroll
      for (int j = 0; j < 4; ++j) acc[i][h][j] = 0.f;

  for (int k0 = 0; k0 < 128; k0 += KC) {
    __syncthreads();
    constexpr int WQ = KC * COLS / 4;
    const float4* wg = (const float4*)(W + k0 * COLS);
#pragma unroll
    for (int i = tid; i < WQ; i += 256) ((float4*)Ws)[i] = wg[i];
#pragma unroll
    for (int i = tid; i < 64 * KC / 4; i += 256) {
      int row = i >> 4;
      int kq = i & 15;
      int gr = r0 + row;
      if (gr > N - 1) gr = N - 1;
      float4 v = *(const float4*)(X + (size_t)gr * 128 + k0 + kq * 4);
      *(float4*)(&Xs[row * XS + kq * 4]) = v;
    }
    __syncthreads();
#pragma unroll
    for (int kk0 = 0; kk0 < KC; kk0 += 4) {
      float4 xv[4];
#pragma unroll
      for (int i = 0; i < 4; ++i)
        xv[i] = *(const float4*)(&Xs[(ty * 4 + i) * XS + kk0]);
#pragma unroll
      for (int t = 0; t < 4; ++t) {
        float4 w0 = *(const float4*)(&Ws[(kk0 + t) * COLS + tx * 4]);
        float4 w1;
        if constexpr (COLS == 128) w1 = *(const float4*)(&Ws[(kk0 + t) * COLS + 64 + tx * 4]);
#pragma unroll
        for (int i = 0; i < 4; ++i) {
          float xk = f4c(xv[i], t);
          acc[i][0][0] = fmaf(xk, w0.x, acc[i][0][0]);
          acc[i][0][1] = fmaf(xk, w0.y, acc[i][0][1]);
          acc[i][0][2] = fmaf(xk, w0.z, acc[i][0][2]);
          acc[i][0][3] = fmaf(xk, w0.w, acc[i][0][3]);
          if constexpr (COLS == 128) {
            acc[i][1][0] = fmaf(xk, w1.x, acc[i][1][0]);
            acc[i][1][1] = fmaf(xk, w1.y, acc[i][1][1]);
            acc[i][1][2] = fmaf(xk, w1.z, acc[i][1][2]);
            acc[i][1][3] = fmaf(xk, w1.w, acc[i][1][3]);
          }
        }
      }
    }
  }

  float4 alv0 = *(const float4*)(al + tx * 4);
  float4 arv0 = *(const float4*)(ar + tx * 4);
  float4 alv1, arv1;
  if constexpr (COLS == 128) {
    alv1 = *(const float4*)(al + 64 + tx * 4);
    arv1 = *(const float4*)(ar + 64 + tx * 4);
  }
#pragma unroll
  for (int i = 0; i < 4; ++i) {
    int r = r0 + ty * 4 + i;
    bool ok = r < N;
    float4 o0 = make_float4(acc[i][0][0], acc[i][0][1], acc[i][0][2], acc[i][0][3]);
    float pl = o0.x * alv0.x + o0.y * alv0.y + o0.z * alv0.z + o0.w * alv0.w;
    float pr = o0.x * arv0.x + o0.y * arv0.y + o0.z * arv0.z + o0.w * arv0.w;
    if (ok) *(float4*)(&H[(size_t)r * COLS + tx * 4]) = o0;
    if constexpr (COLS == 128) {
      float4 o1 = make_float4(acc[i][1][0], acc[i][1][1], acc[i][1][2], acc[i][1][3]);
      pl += o1.x * alv1.x + o1.y * alv1.y + o1.z * alv1.z + o1.w * alv1.w;
      pr += o1.x * arv1.x + o1.y * arv1.y + o1.z * arv1.z + o1.w * arv1.w;
      if (ok) *(float4*)(&H[(size_t)r * COLS + 64 + tx * 4]) = o1;
    }
#pragma unroll
    for (int off = 1; off < 16; off <<= 1) {
      pl += __shfl_xor(pl, off);
      pr += __shfl_xor(pr, off);
    }
    if (ok && tx == 0) {
      hl[r] = pl;
      hr[r] = pr;
    }
  }
}

// ---------------- per-node attention + aggregation ----------------
// Wave = 8 groups x 8 lanes. Each GROUP owns one node (degree-sorted via perm,
// so the 8 nodes in a wave have near-equal degree -> minimal divergence).
// Lane l owns feature elements [l*EPL, (l+1)*EPL). Defer-max online softmax:
// keep m from first edge, only rescale if alpha jumps by >30 (exp headroom).
template <int COLS, bool LAST>
__global__ __launch_bounds__(256) void node_kernel(
    const float* __restrict__ H, const float* __restrict__ hl,
    const float* __restrict__ hr, const int* __restrict__ rowptr,
    const int* __restrict__ csr_src, const int* __restrict__ perm,
    const float* __restrict__ b, float* __restrict__ OUT, int N) {
  constexpr int GS = 8;
  constexpr int EPL = COLS / GS;  // 16 (COLS=128) or 8 (COLS=64)
  constexpr int NF4 = EPL / 4;
  const int lane = threadIdx.x & 63;
  const int g = lane >> 3, l = lane & 7;
  const int wv = blockIdx.x * 4 + (threadIdx.x >> 6);
  const int idx = wv * GS + g;
  const bool active = idx < N;
  const int node = active ? perm[idx] : 0;

  float hi[EPL];
  {
    const float* hp = H + (size_t)node * COLS + l * EPL;
#pragma unroll
    for (int q = 0; q < NF4; ++q) *(float4*)&hi[q * 4] = *(const float4*)(hp + q * 4);
  }
  const float hri = hr[node];
  int e = active ? rowptr[node] : 0;
  const int end = active ? rowptr[node + 1] : 0;

  float m = -INFINITY, sumw = 0.f;
  float acc[EPL];
#pragma unroll
  for (int j = 0; j < EPL; ++j) acc[j] = 0.f;

  int s;
  float hls;
  float hv[EPL];
  if (e < end) {
    s = csr_src[e];
    hls = hl[s];
    const float* hp = H + (size_t)s * COLS + l * EPL;
#pragma unroll
    for (int q = 0; q < NF4; ++q) *(float4*)&hv[q * 4] = *(const float4*)(hp + q * 4);
  }

  for (; e < end; ++e) {
    float ch[EPL];
#pragma unroll
    for (int j = 0; j < EPL; ++j) ch[j] = hv[j];
    const float chl = hls;
    if (e + 1 < end) {  // group-uniform prefetch
      s = csr_src[e + 1];
      hls = hl[s];
      const float* hp = H + (size_t)s * COLS + l * EPL;
#pragma unroll
      for (int q = 0; q < NF4; ++q) *(float4*)&hv[q * 4] = *(const float4*)(hp + q * 4);
    }
    float d = 0.f;
#pragma unroll
    for (int j = 0; j < EPL; ++j) d = fmaf(hi[j], ch[j], d);
    d += __shfl_xor(d, 1);
    d += __shfl_xor(d, 2);
    d += __shfl_xor(d, 4);
    float gate = 1.f / (1.f + __expf(-d));
    float a = (chl + hri) * gate;
    a = (a >= 0.f) ? a : 0.2f * a;
    float dm = a - m;
    if (dm > 30.f) {             // first edge (m=-inf) or rare big jump
      float sc = __expf(-dm);    // exp(m - a); first edge: exp(-inf) = 0
      sumw *= sc;
#pragma unroll
      for (int j = 0; j < EPL; ++j) acc[j] *= sc;
      m = a;
      dm = 0.f;
    }
    float w = __expf(dm);        // may exceed 1 (bounded by e^30) - f32 safe
    sumw += w;
#pragma unroll
    for (int j = 0; j < EPL; ++j) acc[j] = fmaf(w, ch[j], acc[j]);
  }

  if (!active) return;
  const float inv = 1.f / (sumw + 1e-16f);
  float o[EPL];
  const float* bp = b + l * EPL;
#pragma unroll
  for (int j = 0; j < EPL; ++j) o[j] = fmaxf(acc[j] * inv + bp[j], 0.f);

  if constexpr (LAST) {
    // COLS == 64, EPL == 8: log_softmax over the group's 64 values
    float mx = o[0];
#pragma unroll
    for (int j = 1; j < EPL; ++j) mx = fmaxf(mx, o[j]);
    mx = fmaxf(mx, __shfl_xor(mx, 1));
    mx = fmaxf(mx, __shfl_xor(mx, 2));
    mx = fmaxf(mx, __shfl_xor(mx, 4));
    float es = 0.f;
#pragma unroll
    for (int j = 0; j < EPL; ++j) es += __expf(o[j] - mx);
    es += __shfl_xor(es, 1);
    es += __shfl_xor(es, 2);
    es += __shfl_xor(es, 4);
    float ls = logf(es);
#pragma unroll
    for (int q = 0; q < NF4; ++q) {
      float4 ov = make_float4(o[q * 4 + 0] - mx - ls, o[q * 4 + 1] - mx - ls,
                              o[q * 4 + 2] - mx - ls, o[q * 4 + 3] - mx - ls);
      *(float4*)(&OUT[(size_t)node * COLS + l * EPL + q * 4]) = ov;
    }
  } else {
#pragma unroll
    for (int q = 0; q < NF4; ++q) {
      float4 ov = make_float4(o[q * 4 + 0], o[q * 4 + 1], o[q * 4 + 2], o[q * 4 + 3]);
      *(float4*)(&OUT[(size_t)node * COLS + l * EPL + q * 4]) = ov;
    }
  }
}

// ---------------- launch ----------------
extern "C" void kernel_launch(void* const* d_in, const int* in_sizes, int n_in,
                              void* d_out, int out_size, void* d_ws, size_t ws_size,
                              hipStream_t stream) {
  const float* x = (const float*)d_in[0];
  const int* ei = (const int*)d_in[1];
  const float* W0 = (const float*)d_in[2];
  const float* al0 = (const float*)d_in[3];
  const float* ar0 = (const float*)d_in[4];
  const float* b0 = (const float*)d_in[5];
  const float* W1 = (const float*)d_in[6];
  const float* al1 = (const float*)d_in[7];
  const float* ar1 = (const float*)d_in[8];
  const float* b1 = (const float*)d_in[9];
  const float* W2 = (const float*)d_in[10];
  const float* al2 = (const float*)d_in[11];
  const float* ar2 = (const float*)d_in[12];
  const float* b2 = (const float*)d_in[13];

  const int N = in_sizes[0] / 128;  // 50000
  const int E = in_sizes[1] / 2;    // 640000
  const int ETOT = E + N;

  char* p = (char*)d_ws;
  auto carve = [&](size_t bytes) {
    void* r = (void*)p;
    p += (bytes + 255) & ~(size_t)255;
    return r;
  };
  float* hA = (float*)carve((size_t)N * 128 * sizeof(float));
  float* hB = (float*)carve((size_t)N * 128 * sizeof(float));
  float* hl = (float*)carve((size_t)N * sizeof(float));
  float* hr = (float*)carve((size_t)N * sizeof(float));
  int* counts = (int*)carve((size_t)N * sizeof(int));
  int* excl = (int*)carve((size_t)N * sizeof(int));
  int* bsums = (int*)carve(1024 * sizeof(int));
  int* rowptr = (int*)carve((size_t)(N + 1) * sizeof(int));
  int* cursor = (int*)carve((size_t)(N + 1) * sizeof(int));
  int* csr_src = (int*)carve((size_t)ETOT * sizeof(int));
  int* dhist = (int*)carve(1024 * sizeof(int));
  int* perm = (int*)carve((size_t)N * sizeof(int));

  // ---- CSR build ----
  hipMemsetAsync(counts, 0, (size_t)N * sizeof(int), stream);
  hipMemsetAsync(dhist, 0, 1024 * sizeof(int), stream);
  {
    int nb = (ETOT + 255) / 256;
    histo_kernel<<<nb, 256, 0, stream>>>(ei, E, N, counts);
  }
  int nbs = (N + 255) / 256;
  scan1_kernel<<<nbs, 256, 0, stream>>>(counts, excl, bsums, N);
  scan2_kernel<<<1, 256, 0, stream>>>(bsums, nbs);
  scan3_kernel<<<(N + 256) / 256 + 1, 256, 0, stream>>>(excl, bsums, rowptr, cursor, N, ETOT);
  {
    int nb = (ETOT + 255) / 256;
    scatter_kernel<<<nb, 256, 0, stream>>>(ei, E, N, cursor, csr_src);
  }
  // ---- degree sort (LDS-aggregated counting sort) ----
  deghist_kernel<<<nbs, 256, 0, stream>>>(rowptr, N, dhist);
  degscan_kernel<<<1, 1024, 0, stream>>>(dhist);
  degscatter_kernel<<<nbs, 256, 0, stream>>>(rowptr, N, dhist, perm);

  const int gemm_grid = (N + 63) / 64;
  const int node_grid = (N + 31) / 32;  // 32 nodes per block (4 waves x 8 groups)

  gemm_kernel<128><<<gemm_grid, 256, 0, stream>>>(x, W0, al0, ar0, hA, hl, hr, N);
  node_kernel<128, false><<<node_grid, 256, 0, stream>>>(hA, hl, hr, rowptr, csr_src, perm, b0, hB, N);

  gemm_kernel<128><<<gemm_grid, 256, 0, stream>>>(hB, W1, al1, ar1, hA, hl, hr, N);
  node_kernel<128, false><<<node_grid, 256, 0, stream>>>(hA, hl, hr, rowptr, csr_src, perm, b1, hB, N);

  gemm_kernel<64><<<gemm_grid, 256, 0, stream>>>(hB, W2, al2, ar2, hA, hl, hr, N);
  node_kernel<64, true><<<node_grid, 256, 0, stream>>>(hA, hl, hr, rowptr, csr_src, perm, b2,
                                                       (float*)d_out, N);
}

// Round 6
// 340.056 us; speedup vs baseline: 1.9021x; 1.0293x over previous
//
#include <hip/hip_runtime.h>
#include <math.h>

__device__ __forceinline__ float f4c(const float4& v, int t) {
  return t == 0 ? v.x : t == 1 ? v.y : t == 2 ? v.z : v.w;
}

// ---------------- CSR build ----------------
__global__ void histo_kernel(const int* __restrict__ ei, int E, int N,
                             int* __restrict__ counts) {
  int e = blockIdx.x * blockDim.x + threadIdx.x;
  int etot = E + N;
  if (e >= etot) return;
  int d = (e < E) ? ei[E + e] : (e - E);
  atomicAdd(&counts[d], 1);
}

__global__ void scan1_kernel(const int* __restrict__ counts, int* __restrict__ excl,
                             int* __restrict__ bsums, int N) {
  __shared__ int sm[256];
  int t = threadIdx.x;
  int i = blockIdx.x * 256 + t;
  int v = (i < N) ? counts[i] : 0;
  sm[t] = v;
  __syncthreads();
#pragma unroll
  for (int off = 1; off < 256; off <<= 1) {
    int add = (t >= off) ? sm[t - off] : 0;
    __syncthreads();
    sm[t] += add;
    __syncthreads();
  }
  if (i < N) excl[i] = sm[t] - v;
  if (t == 255) bsums[blockIdx.x] = sm[255];
}

__global__ void scan2_kernel(int* __restrict__ bsums, int nb) {
  __shared__ int sm[256];
  int t = threadIdx.x;
  int v = (t < nb) ? bsums[t] : 0;
  sm[t] = v;
  __syncthreads();
#pragma unroll
  for (int off = 1; off < 256; off <<= 1) {
    int add = (t >= off) ? sm[t - off] : 0;
    __syncthreads();
    sm[t] += add;
    __syncthreads();
  }
  if (t < nb) bsums[t] = sm[t] - v;  // exclusive
}

__global__ void scan3_kernel(const int* __restrict__ excl, const int* __restrict__ bsums,
                             int* __restrict__ rowptr, int* __restrict__ cursor,
                             int N, int etot) {
  int i = blockIdx.x * 256 + threadIdx.x;
  if (i < N) {
    int v = excl[i] + bsums[i >> 8];
    rowptr[i] = v;
    cursor[i] = v;
  }
  if (i == N) rowptr[N] = etot;
}

__global__ void scatter_kernel(const int* __restrict__ ei, int E, int N,
                               int* __restrict__ cursor, int* __restrict__ csr_src) {
  int e = blockIdx.x * blockDim.x + threadIdx.x;
  int etot = E + N;
  if (e >= etot) return;
  int s, d;
  if (e < E) { s = ei[e]; d = ei[E + e]; } else { s = e - E; d = e - E; }
  int pos = atomicAdd(&cursor[d], 1);
  csr_src[pos] = s;
}

// ---------------- degree counting-sort, LDS-aggregated ----------------
__global__ void deghist_kernel(const int* __restrict__ rowptr, int N,
                               int* __restrict__ dhist) {
  __shared__ int lh[1024];
  int t = threadIdx.x;
  for (int i = t; i < 1024; i += 256) lh[i] = 0;
  __syncthreads();
  int i = blockIdx.x * 256 + t;
  if (i < N) {
    int d = rowptr[i + 1] - rowptr[i];
    int key = d < 1023 ? d : 1023;
    atomicAdd(&lh[key], 1);
  }
  __syncthreads();
  for (int bin = t; bin < 1024; bin += 256) {
    int c = lh[bin];
    if (c) atomicAdd(&dhist[bin], c);
  }
}

__global__ void degscan_kernel(int* __restrict__ dhist) {  // 1 block x 1024
  __shared__ int sm[1024];
  int t = threadIdx.x;
  int v = dhist[t];
  sm[t] = v;
  __syncthreads();
#pragma unroll
  for (int off = 1; off < 1024; off <<= 1) {
    int add = (t >= off) ? sm[t - off] : 0;
    __syncthreads();
    sm[t] += add;
    __syncthreads();
  }
  dhist[t] = sm[t] - v;  // exclusive
}

__global__ void degscatter_kernel(const int* __restrict__ rowptr, int N,
                                  int* __restrict__ dhist, int* __restrict__ perm) {
  __shared__ int lc[1024];
  __shared__ int lb[1024];
  int t = threadIdx.x;
  for (int i = t; i < 1024; i += 256) lc[i] = 0;
  __syncthreads();
  int i = blockIdx.x * 256 + t;
  int key = 0, lr = 0;
  if (i < N) {
    int d = rowptr[i + 1] - rowptr[i];
    key = d < 1023 ? d : 1023;
    lr = atomicAdd(&lc[key], 1);
  }
  __syncthreads();
  for (int bin = t; bin < 1024; bin += 256) {
    int c = lc[bin];
    if (c) lb[bin] = atomicAdd(&dhist[bin], c);
  }
  __syncthreads();
  if (i < N) perm[lb[key] + lr] = i;
}

// ---------------- GEMM: H = X(N x 128) @ W(128 x COLS) + hl/hr epilogue -------
template <int COLS>
__global__ __launch_bounds__(256) void gemm_kernel(
    const float* __restrict__ X, const float* __restrict__ W,
    const float* __restrict__ al, const float* __restrict__ ar,
    float* __restrict__ H, float* __restrict__ hl, float* __restrict__ hr, int N) {
  constexpr int KC = 64;
  constexpr int XS = KC + 4;  // 2-way bank alias (free)
  __shared__ float Ws[KC * COLS];
  __shared__ float Xs[64 * XS];
  const int tid = threadIdx.x;
  const int tx = tid & 15, ty = tid >> 4;
  const int r0 = blockIdx.x * 64;

  float acc[4][2][4];
#pragma unroll
  for (int i = 0; i < 4; ++i)
#pragma unroll
    for (int h = 0; h < 2; ++h)
#pragma unroll
      for (int j = 0; j < 4; ++j) acc[i][h][j] = 0.f;

  for (int k0 = 0; k0 < 128; k0 += KC) {
    __syncthreads();
    constexpr int WQ = KC * COLS / 4;
    const float4* wg = (const float4*)(W + k0 * COLS);
#pragma unroll
    for (int i = tid; i < WQ; i += 256) ((float4*)Ws)[i] = wg[i];
#pragma unroll
    for (int i = tid; i < 64 * KC / 4; i += 256) {
      int row = i >> 4;
      int kq = i & 15;
      int gr = r0 + row;
      if (gr > N - 1) gr = N - 1;
      float4 v = *(const float4*)(X + (size_t)gr * 128 + k0 + kq * 4);
      *(float4*)(&Xs[row * XS + kq * 4]) = v;
    }
    __syncthreads();
#pragma unroll
    for (int kk0 = 0; kk0 < KC; kk0 += 4) {
      float4 xv[4];
#pragma unroll
      for (int i = 0; i < 4; ++i)
        xv[i] = *(const float4*)(&Xs[(ty * 4 + i) * XS + kk0]);
#pragma unroll
      for (int t = 0; t < 4; ++t) {
        float4 w0 = *(const float4*)(&Ws[(kk0 + t) * COLS + tx * 4]);
        float4 w1;
        if constexpr (COLS == 128) w1 = *(const float4*)(&Ws[(kk0 + t) * COLS + 64 + tx * 4]);
#pragma unroll
        for (int i = 0; i < 4; ++i) {
          float xk = f4c(xv[i], t);
          acc[i][0][0] = fmaf(xk, w0.x, acc[i][0][0]);
          acc[i][0][1] = fmaf(xk, w0.y, acc[i][0][1]);
          acc[i][0][2] = fmaf(xk, w0.z, acc[i][0][2]);
          acc[i][0][3] = fmaf(xk, w0.w, acc[i][0][3]);
          if constexpr (COLS == 128) {
            acc[i][1][0] = fmaf(xk, w1.x, acc[i][1][0]);
            acc[i][1][1] = fmaf(xk, w1.y, acc[i][1][1]);
            acc[i][1][2] = fmaf(xk, w1.z, acc[i][1][2]);
            acc[i][1][3] = fmaf(xk, w1.w, acc[i][1][3]);
          }
        }
      }
    }
  }

  float4 alv0 = *(const float4*)(al + tx * 4);
  float4 arv0 = *(const float4*)(ar + tx * 4);
  float4 alv1, arv1;
  if constexpr (COLS == 128) {
    alv1 = *(const float4*)(al + 64 + tx * 4);
    arv1 = *(const float4*)(ar + 64 + tx * 4);
  }
#pragma unroll
  for (int i = 0; i < 4; ++i) {
    int r = r0 + ty * 4 + i;
    bool ok = r < N;
    float4 o0 = make_float4(acc[i][0][0], acc[i][0][1], acc[i][0][2], acc[i][0][3]);
    float pl = o0.x * alv0.x + o0.y * alv0.y + o0.z * alv0.z + o0.w * alv0.w;
    float pr = o0.x * arv0.x + o0.y * arv0.y + o0.z * arv0.z + o0.w * arv0.w;
    if (ok) *(float4*)(&H[(size_t)r * COLS + tx * 4]) = o0;
    if constexpr (COLS == 128) {
      float4 o1 = make_float4(acc[i][1][0], acc[i][1][1], acc[i][1][2], acc[i][1][3]);
      pl += o1.x * alv1.x + o1.y * alv1.y + o1.z * alv1.z + o1.w * alv1.w;
      pr += o1.x * arv1.x + o1.y * arv1.y + o1.z * arv1.z + o1.w * arv1.w;
      if (ok) *(float4*)(&H[(size_t)r * COLS + 64 + tx * 4]) = o1;
    }
#pragma unroll
    for (int off = 1; off < 16; off <<= 1) {
      pl += __shfl_xor(pl, off);
      pr += __shfl_xor(pr, off);
    }
    if (ok && tx == 0) {
      hl[r] = pl;
      hr[r] = pr;
    }
  }
}

// ---------------- per-node attention + aggregation ----------------
// Wave = 8 groups x 8 lanes; each GROUP owns one node. Nodes are degree-sorted
// (perm); wave w of block b takes chunk (w*gridDim.x + b) of 8 consecutive
// sorted nodes -> intra-wave uniformity AND inter-block balance (each block
// gets a light/medium/heavy mix, so all blocks finish together).
// csr_src is prefetched 2 edges ahead so the H[s] gather for iteration e+1
// issues at the top of iteration e with no index-load dependency.
template <int COLS, bool LAST>
__global__ __launch_bounds__(256) void node_kernel(
    const float* __restrict__ H, const float* __restrict__ hl,
    const float* __restrict__ hr, const int* __restrict__ rowptr,
    const int* __restrict__ csr_src, const int* __restrict__ perm,
    const float* __restrict__ b, float* __restrict__ OUT, int N) {
  constexpr int GS = 8;
  constexpr int EPL = COLS / GS;  // 16 (COLS=128) or 8 (COLS=64)
  constexpr int NF4 = EPL / 4;
  const int lane = threadIdx.x & 63;
  const int g = lane >> 3, l = lane & 7;
  const int chunk = (threadIdx.x >> 6) * gridDim.x + blockIdx.x;  // striped
  const int idx = chunk * GS + g;
  const bool active = idx < N;
  const int node = active ? perm[idx] : 0;

  float hi[EPL];
  {
    const float* hp = H + (size_t)node * COLS + l * EPL;
#pragma unroll
    for (int q = 0; q < NF4; ++q) *(float4*)&hi[q * 4] = *(const float4*)(hp + q * 4);
  }
  const float hri = hr[node];
  int e = active ? rowptr[node] : 0;
  const int end = active ? rowptr[node + 1] : 0;

  float m = -INFINITY, sumw = 0.f;
  float acc[EPL];
#pragma unroll
  for (int j = 0; j < EPL; ++j) acc[j] = 0.f;

  float hls;
  float hv[EPL];
  int sB = 0;
  if (e < end) {
    int s0 = csr_src[e];
    hls = hl[s0];
    const float* hp = H + (size_t)s0 * COLS + l * EPL;
#pragma unroll
    for (int q = 0; q < NF4; ++q) *(float4*)&hv[q * 4] = *(const float4*)(hp + q * 4);
    if (e + 1 < end) sB = csr_src[e + 1];  // index for e+1 already resident
  }

  for (; e < end; ++e) {
    float ch[EPL];
#pragma unroll
    for (int j = 0; j < EPL; ++j) ch[j] = hv[j];
    const float chl = hls;
    // issue next-edge gather immediately (index already in register)
    if (e + 1 < end) {
      hls = hl[sB];
      const float* hp = H + (size_t)sB * COLS + l * EPL;
#pragma unroll
      for (int q = 0; q < NF4; ++q) *(float4*)&hv[q * 4] = *(const float4*)(hp + q * 4);
    }
    int sC = (e + 2 < end) ? csr_src[e + 2] : 0;  // overlaps with compute below
    float d = 0.f;
#pragma unroll
    for (int j = 0; j < EPL; ++j) d = fmaf(hi[j], ch[j], d);
    d += __shfl_xor(d, 1);
    d += __shfl_xor(d, 2);
    d += __shfl_xor(d, 4);
    float gate = 1.f / (1.f + __expf(-d));
    float a = (chl + hri) * gate;
    a = (a >= 0.f) ? a : 0.2f * a;
    float dm = a - m;
    if (dm > 30.f) {             // first edge (m=-inf) or rare big jump
      float sc = __expf(-dm);    // exp(m - a); first edge: exp(-inf) = 0
      sumw *= sc;
#pragma unroll
      for (int j = 0; j < EPL; ++j) acc[j] *= sc;
      m = a;
      dm = 0.f;
    }
    float w = __expf(dm);        // bounded by e^30 - f32 safe
    sumw += w;
#pragma unroll
    for (int j = 0; j < EPL; ++j) acc[j] = fmaf(w, ch[j], acc[j]);
    sB = sC;
  }

  if (!active) return;
  const float inv = 1.f / (sumw + 1e-16f);
  float o[EPL];
  const float* bp = b + l * EPL;
#pragma unroll
  for (int j = 0; j < EPL; ++j) o[j] = fmaxf(acc[j] * inv + bp[j], 0.f);

  if constexpr (LAST) {
    // COLS == 64, EPL == 8: log_softmax over the group's 64 values
    float mx = o[0];
#pragma unroll
    for (int j = 1; j < EPL; ++j) mx = fmaxf(mx, o[j]);
    mx = fmaxf(mx, __shfl_xor(mx, 1));
    mx = fmaxf(mx, __shfl_xor(mx, 2));
    mx = fmaxf(mx, __shfl_xor(mx, 4));
    float es = 0.f;
#pragma unroll
    for (int j = 0; j < EPL; ++j) es += __expf(o[j] - mx);
    es += __shfl_xor(es, 1);
    es += __shfl_xor(es, 2);
    es += __shfl_xor(es, 4);
    float ls = logf(es);
#pragma unroll
    for (int q = 0; q < NF4; ++q) {
      float4 ov = make_float4(o[q * 4 + 0] - mx - ls, o[q * 4 + 1] - mx - ls,
                              o[q * 4 + 2] - mx - ls, o[q * 4 + 3] - mx - ls);
      *(float4*)(&OUT[(size_t)node * COLS + l * EPL + q * 4]) = ov;
    }
  } else {
#pragma unroll
    for (int q = 0; q < NF4; ++q) {
      float4 ov = make_float4(o[q * 4 + 0], o[q * 4 + 1], o[q * 4 + 2], o[q * 4 + 3]);
      *(float4*)(&OUT[(size_t)node * COLS + l * EPL + q * 4]) = ov;
    }
  }
}

// ---------------- launch ----------------
extern "C" void kernel_launch(void* const* d_in, const int* in_sizes, int n_in,
                              void* d_out, int out_size, void* d_ws, size_t ws_size,
                              hipStream_t stream) {
  const float* x = (const float*)d_in[0];
  const int* ei = (const int*)d_in[1];
  const float* W0 = (const float*)d_in[2];
  const float* al0 = (const float*)d_in[3];
  const float* ar0 = (const float*)d_in[4];
  const float* b0 = (const float*)d_in[5];
  const float* W1 = (const float*)d_in[6];
  const float* al1 = (const float*)d_in[7];
  const float* ar1 = (const float*)d_in[8];
  const float* b1 = (const float*)d_in[9];
  const float* W2 = (const float*)d_in[10];
  const float* al2 = (const float*)d_in[11];
  const float* ar2 = (const float*)d_in[12];
  const float* b2 = (const float*)d_in[13];

  const int N = in_sizes[0] / 128;  // 50000
  const int E = in_sizes[1] / 2;    // 640000
  const int ETOT = E + N;

  char* p = (char*)d_ws;
  auto carve = [&](size_t bytes) {
    void* r = (void*)p;
    p += (bytes + 255) & ~(size_t)255;
    return r;
  };
  float* hA = (float*)carve((size_t)N * 128 * sizeof(float));
  float* hB = (float*)carve((size_t)N * 128 * sizeof(float));
  float* hl = (float*)carve((size_t)N * sizeof(float));
  float* hr = (float*)carve((size_t)N * sizeof(float));
  int* counts = (int*)carve((size_t)N * sizeof(int));
  int* excl = (int*)carve((size_t)N * sizeof(int));
  int* bsums = (int*)carve(1024 * sizeof(int));
  int* rowptr = (int*)carve((size_t)(N + 1) * sizeof(int));
  int* cursor = (int*)carve((size_t)(N + 1) * sizeof(int));
  int* csr_src = (int*)carve((size_t)ETOT * sizeof(int));
  int* dhist = (int*)carve(1024 * sizeof(int));
  int* perm = (int*)carve((size_t)N * sizeof(int));

  // ---- CSR build ----
  hipMemsetAsync(counts, 0, (size_t)N * sizeof(int), stream);
  hipMemsetAsync(dhist, 0, 1024 * sizeof(int), stream);
  {
    int nb = (ETOT + 255) / 256;
    histo_kernel<<<nb, 256, 0, stream>>>(ei, E, N, counts);
  }
  int nbs = (N + 255) / 256;
  scan1_kernel<<<nbs, 256, 0, stream>>>(counts, excl, bsums, N);
  scan2_kernel<<<1, 256, 0, stream>>>(bsums, nbs);
  scan3_kernel<<<(N + 256) / 256 + 1, 256, 0, stream>>>(excl, bsums, rowptr, cursor, N, ETOT);
  {
    int nb = (ETOT + 255) / 256;
    scatter_kernel<<<nb, 256, 0, stream>>>(ei, E, N, cursor, csr_src);
  }
  // ---- degree sort (LDS-aggregated counting sort) ----
  deghist_kernel<<<nbs, 256, 0, stream>>>(rowptr, N, dhist);
  degscan_kernel<<<1, 1024, 0, stream>>>(dhist);
  degscatter_kernel<<<nbs, 256, 0, stream>>>(rowptr, N, dhist, perm);

  const int gemm_grid = (N + 63) / 64;
  const int node_grid = (N + 31) / 32;  // 4 waves x 8 groups = 32 nodes/block

  gemm_kernel<128><<<gemm_grid, 256, 0, stream>>>(x, W0, al0, ar0, hA, hl, hr, N);
  node_kernel<128, false><<<node_grid, 256, 0, stream>>>(hA, hl, hr, rowptr, csr_src, perm, b0, hB, N);

  gemm_kernel<128><<<gemm_grid, 256, 0, stream>>>(hB, W1, al1, ar1, hA, hl, hr, N);
  node_kernel<128, false><<<node_grid, 256, 0, stream>>>(hA, hl, hr, rowptr, csr_src, perm, b1, hB, N);

  gemm_kernel<64><<<gemm_grid, 256, 0, stream>>>(hB, W2, al2, ar2, hA, hl, hr, N);
  node_kernel<64, true><<<node_grid, 256, 0, stream>>>(hA, hl, hr, rowptr, csr_src, perm, b2,
                                                       (float*)d_out, N);
}